// Round 8
// baseline (220.504 us; speedup 1.0000x reference)
//
#include <hip/hip_runtime.h>

// SAGE 2-layer GraphSAGE (mean aggr) on MI355X.
// Pipeline: setup(bin+convert+prep) -> fill2 -> [agg -> gemm] x2. (6 kernels)
// R1: hierarchical scan (single-block scan was 108us on 1 CU).
// R2: bucket-local CSR build (random scatter had 16x write amplification).
// R3: LDS-free GEMM w/ pre-formatted bf16 B-frags (bank conflicts + 2 blk/CU).
// R4-R6: fused setup (bin blocks FIRST in grid), fill2 block=1024.
// R7: REGRESSION: agg fused into gemm block cut agg waves 50000->3128 (79us).
//     agg must keep 1 wave/node.
// R8: best=228.0us.
// R9: REGRESSION (245us): NBIN 1568 fragmented staging; NBIN=784 optimum.
// R10: REGRESSION (288us): slice-phased agg. Bottleneck is NOT cache tier.
// R11: 215.7us. agg: coalesced csr + readlane broadcast + 8-deep gathers.
// R12: REGRESSION (228.7us): persistent agg. Wave retirement IS the pipeline.
// R13: NEUTRAL (218.6us): depth 8->16 alone. Load depth saturated.
// R14: 209.9us. Scalar-pipe diet: s_load indices, saddr gathers, v_pk_add_f32.
// R15: 206.4us. Single-wait 32-slot batch for deg<=31. agg now within ~15%
//      of its request-path floor (~3.2M compulsory 64B lines @ ~5-6 TB/s).
// R16: kill memset dispatch + setup's global-atomic WAIT: staging becomes
//      fixed per-(binblock,bucket) slices (cap 40, P(ovfl)~1e-13/cell); bin
//      blocks use only LDS counters + write counts[784][196]; fill2 column-
//      sums counts for bucket totals and gathers from slices. Same ~21B
//      write-run granularity as before (R9 regression does not re-apply).
// R17: resubmit of R16 (round 7 bench was an infra failure, no data).

typedef __attribute__((ext_vector_type(8))) short short8;
typedef __attribute__((ext_vector_type(4))) float f32x4;
typedef __attribute__((ext_vector_type(2))) float f32x2;

#define DEV __device__ __forceinline__

DEV unsigned short f2b(float f) {
  unsigned u = __builtin_bit_cast(unsigned, f);
  u += 0x7fffu + ((u >> 16) & 1u);   // round-to-nearest-even
  return (unsigned short)(u >> 16);
}
DEV float b2f(unsigned short h) {
  unsigned u = ((unsigned)h) << 16;
  return __builtin_bit_cast(float, u);
}
DEV float bitf(unsigned u) { return __builtin_bit_cast(float, u); }

constexpr int N_NODES = 50000;
constexpr int N_EDGES = 800000;
constexpr int D = 128;
constexpr int NBUCK = (N_NODES + 255) / 256;          // 196 buckets of 256 nodes
constexpr int NBIN = 784;                             // bin blocks (3/CU) - measured optimum
constexpr int EPB = (N_EDGES + NBIN - 1) / NBIN;      // 1021 edges per bin block
constexpr int SCAP = 40;                              // slice cap: Bin(1021,1/196) P(>=40) ~ 1e-13
constexpr int NCONV = (N_NODES * D / 4) / 256;        // 6250 convert blocks
constexpr int NPREP = (2 * 32 * 128) / 256;           // 32 prep blocks

// ---------------- fused setup: bin | convert | prep_weights ----------------
// bin blocks FIRST: latency-bound long pole; convert streams around them.
// R16: bin path has NO global atomics and NO dependence on pre-zeroed memory.
__global__ __launch_bounds__(256) void setup_kernel(
    const float* __restrict__ x, unsigned short* __restrict__ xb,
    const float* __restrict__ Wl0, const float* __restrict__ Wr0,
    const float* __restrict__ Wl1, const float* __restrict__ Wr1,
    unsigned short* __restrict__ Bf,
    const int* __restrict__ src, const int* __restrict__ dst,
    int* __restrict__ counts, unsigned* __restrict__ staging) {
  __shared__ int cnt[NBUCK];
  __shared__ int cur[NBUCK];
  int bid = blockIdx.x;
  int t = threadIdx.x;

  if (bid < NBIN) {
    // bin: bucket edges into this block's own fixed slices, packed
    // (dloc<<16)|src  (src < 2^16)
    for (int i = t; i < NBUCK; i += 256) { cnt[i] = 0; cur[i] = 0; }
    __syncthreads();
    int beg = bid * EPB;
    int end = min(beg + EPB, N_EDGES);
    for (int e = beg + t; e < end; e += 256) {
      atomicAdd(&cnt[dst[e] >> 8], 1);
    }
    __syncthreads();
    for (int i = t; i < NBUCK; i += 256) {
      counts[bid * NBUCK + i] = min(cnt[i], SCAP);
    }
    for (int e = beg + t; e < end; e += 256) {
      int d = dst[e];
      int b = d >> 8;
      int p = atomicAdd(&cur[b], 1);             // LDS-local only
      if (p < SCAP)
        staging[((size_t)bid * NBUCK + b) * SCAP + p] =
            ((unsigned)(d & 255) << 16) | (unsigned)src[e];
    }
    return;
  }
  if (bid < NBIN + NCONV) {
    // fp32 -> bf16 feature convert
    int i = (bid - NBIN) * 256 + t;
    f32x4 v = ((const f32x4*)x)[i];
    uint2 o;
    o.x = (unsigned)f2b(v.x) | ((unsigned)f2b(v.y) << 16);
    o.y = (unsigned)f2b(v.z) | ((unsigned)f2b(v.w) << 16);
    ((uint2*)xb)[i] = o;
    return;
  }
  // weights fp32 [out][in] -> bf16 B-fragment order (frag = kchunk*128+n)
  int f = (bid - NBIN - NCONV) * 256 + t;
  int layer = f >> 12;
  int kchunk = (f >> 7) & 31;
  int n = f & 127;
  const float* W;
  if (layer == 0) W = (kchunk < 16) ? Wl0 : Wr0;
  else            W = (kchunk < 16) ? Wl1 : Wr1;
  int k = (kchunk & 15) * 8;
  const f32x4* row = (const f32x4*)(W + n * D + k);
  f32x4 a = row[0], b = row[1];
  uint4 pk;
  pk.x = (unsigned)f2b(a.x) | ((unsigned)f2b(a.y) << 16);
  pk.y = (unsigned)f2b(a.z) | ((unsigned)f2b(a.w) << 16);
  pk.z = (unsigned)f2b(b.x) | ((unsigned)f2b(b.y) << 16);
  pk.w = (unsigned)f2b(b.z) | ((unsigned)f2b(b.w) << 16);
  *(uint4*)(Bf + (size_t)f * 8) = pk;
}

// ---------------- fill2: counts-matrix scan + per-bucket CSR fill ----------
// One block per bucket (196 x 1024). Bucket totals from column sums of
// counts[784][196]; edges gathered from fixed slices (no dense staging).
__global__ __launch_bounds__(1024) void fill2_kernel(const unsigned* __restrict__ staging,
                                                     const int* __restrict__ counts,
                                                     int* __restrict__ offs,
                                                     int* __restrict__ csr) {
  __shared__ int totals[256];
  __shared__ int tmp[256];
  __shared__ int hist[256];
  __shared__ int cur[256];
  __shared__ int sh_n, sh_bb;
  int b = blockIdx.x;
  int t = threadIdx.x;
  if (t < 256) hist[t] = 0;
  __syncthreads();

  // phase A: per-slice histogram (thread t owns bin-block t's slice of bucket b)
  int myc = 0;
  const unsigned* sl = nullptr;
  if (t < NBIN) {
    myc = counts[t * NBUCK + b];
    sl = staging + ((size_t)t * NBUCK + b) * SCAP;
    for (int k = 0; k < myc; ++k) atomicAdd(&hist[sl[k] >> 16], 1);
  }
  // phase B: bucket totals via column sums (threads 0..195)
  if (t < 256) {
    int s = 0;
    if (t < NBUCK) {
      for (int r = 0; r < NBIN; ++r) s += counts[r * NBUCK + t];
    }
    totals[t] = s;
    tmp[t] = s;
  }
  __syncthreads();
  // scan totals -> cross-bucket exclusive base
  if (t < 256) {
    for (int off = 1; off < 256; off <<= 1) {
      int u = (t >= off) ? tmp[t - off] : 0;
      __syncthreads();
      tmp[t] += u;
      __syncthreads();
    }
  } else {
    for (int off = 1; off < 256; off <<= 1) { __syncthreads(); __syncthreads(); }
  }
  if (t == 0) {
    sh_n = totals[b];
    sh_bb = tmp[b] - totals[b];   // exclusive prefix for this bucket
  }
  __syncthreads();
  int bb = sh_bb;
  (void)sh_n;
  if (b == 0 && t == 0) offs[N_NODES] = N_EDGES;

  // per-node scan of hist -> offs + cur bases
  if (t < 256) {
    int v = hist[t];
    tmp[t] = v;
    __syncthreads();
    for (int off = 1; off < 256; off <<= 1) {
      int u = (t >= off) ? tmp[t - off] : 0;
      __syncthreads();
      tmp[t] += u;
      __syncthreads();
    }
    int excl = tmp[t] - v;
    int node = b * 256 + t;
    if (node < N_NODES) offs[node] = bb + excl;
    cur[t] = bb + excl;
  } else {
    __syncthreads();
    for (int off = 1; off < 256; off <<= 1) { __syncthreads(); __syncthreads(); }
  }
  __syncthreads();
  // phase C: scatter slices into CSR
  if (t < NBIN) {
    for (int k = 0; k < myc; ++k) {
      unsigned pk = sl[k];
      int p = atomicAdd(&cur[pk >> 16], 1);
      csr[p] = (int)(pk & 0xffffu);
    }
  }
}

// ---------------- mean aggregation: one wave per node ----------------
// 50000 waves; each lane owns one dword (2 cols); fp32 accumulate.
// R14: uniform wave id -> offs/csr via scalar loads, saddr gathers,
//      f32x2 accumulator (v_pk_add_f32). ~3 VALU/edge.
// R15: deg<=31 (99.6% of nodes): ONE 32-slot gather batch -> one wait.
__global__ __launch_bounds__(256) void agg_kernel(
    const unsigned short* __restrict__ feat,
    const int* __restrict__ csr_src,
    const int* __restrict__ offs,
    unsigned short* __restrict__ out) {
  int wv = __builtin_amdgcn_readfirstlane((int)(threadIdx.x >> 6));
  int w = (int)blockIdx.x * 4 + wv;
  int lane = threadIdx.x & 63;
  if (w >= N_NODES) return;
  int s = __builtin_amdgcn_readfirstlane(offs[w]);
  int e = __builtin_amdgcn_readfirstlane(offs[w + 1]);
  int deg = e - s;
  const unsigned* f = (const unsigned*)feat;  // 64 dwords per row
  const int* p = csr_src + s;                 // uniform base -> s_load
  f32x2 acc = {0.f, 0.f};

  if (deg <= 31) {
    // single gather round: issue everything, then one wait at first use.
    unsigned u[32];
#pragma unroll
    for (int jb = 0; jb < 32; jb += 4) {
      if (jb < deg) {
#pragma unroll
        for (int j2 = 0; j2 < 4; ++j2) {
          unsigned sj = (unsigned)p[jb + j2] & 0xFFFFu;  // clamped over-read
          u[jb + j2] = f[(sj << 6) + lane];
        }
      }
    }
#pragma unroll
    for (int j = 0; j < 32; ++j) {
      if (j < deg) {
        f32x2 v = {bitf(u[j] << 16), bitf(u[j] & 0xffff0000u)};
        acc += v;                                // v_pk_add_f32
      }
    }
  } else {
    // rare (P ~ 0.4%): R14 batched loop
    int c = 0;
    for (; c + 16 <= deg; c += 16) {
      unsigned u[16];
#pragma unroll
      for (int j = 0; j < 16; ++j) {
        int sj = p[c + j];
        u[j] = f[((unsigned)sj << 6) + lane];
      }
#pragma unroll
      for (int j = 0; j < 16; ++j) {
        f32x2 v = {bitf(u[j] << 16), bitf(u[j] & 0xffff0000u)};
        acc += v;
      }
    }
    int nb = deg - c;
    unsigned u[16];
#pragma unroll
    for (int j = 0; j < 16; ++j) {
      if (j < nb) {
        int sj = p[c + j];
        u[j] = f[((unsigned)sj << 6) + lane];
      }
    }
#pragma unroll
    for (int j = 0; j < 16; ++j) {
      if (j < nb) {
        f32x2 v = {bitf(u[j] << 16), bitf(u[j] & 0xffff0000u)};
        acc += v;
      }
    }
  }

  float inv = 1.0f / (float)max(deg, 1);
  unsigned o = (unsigned)f2b(acc.x * inv) | ((unsigned)f2b(acc.y * inv) << 16);
  ((unsigned*)out)[(size_t)w * 64 + lane] = o;
}

// ---------------- LDS-free fused SAGE GEMM, 16 nodes/wave ----------------
// out[i,:] = Aagg[i,:] @ Wl^T + Afeat[i,:] @ Wr^T + bias  (+optional ReLU)
// 782 blocks x 4 waves = 3128 waves (measured optimum vs 1564 / 6252).
__global__ __launch_bounds__(256) void gemm_kernel(
    const unsigned short* __restrict__ Aagg,   // [N][128] bf16
    const unsigned short* __restrict__ Afeat,  // [N][128] bf16
    const unsigned short* __restrict__ Bf,     // frag-ordered weights, this layer
    const float* __restrict__ bias,            // [128]
    float* __restrict__ out_f32,               // used if relu_bf16 == 0
    unsigned short* __restrict__ out_bf16,     // used if relu_bf16 == 1
    int relu_bf16) {
  int wave = threadIdx.x >> 6;
  int lane = threadIdx.x & 63;
  int ml = lane & 15;     // A: m / B: n / C: col
  int quad = lane >> 4;   // A,B: k-sub / C: row group
  int node0 = blockIdx.x * 64 + wave * 16;

  int arow = node0 + ml;
  if (arow >= N_NODES) arow = N_NODES - 1;  // clamp; stores guarded below

  f32x4 acc[8];
#pragma unroll
  for (int t = 0; t < 8; ++t) acc[t] = (f32x4){0.f, 0.f, 0.f, 0.f};

  const short8* bf8 = (const short8*)Bf;  // frag idx = kchunk*128 + n
#pragma unroll
  for (int mat = 0; mat < 2; ++mat) {
    const unsigned short* A = mat ? Afeat : Aagg;
    const short8* arow8 = (const short8*)(A + (size_t)arow * D);  // 16 frags/row
    int kbase = mat * 16;
#pragma unroll
    for (int kc = 0; kc < 4; ++kc) {
      short8 af = arow8[kc * 4 + quad];          // A[m][kc*32 + quad*8 ..+8]
      int kchunk = kbase + kc * 4 + quad;
      const short8* brow = bf8 + kchunk * 128;
#pragma unroll
      for (int nt = 0; nt < 8; ++nt) {
        short8 bfr = brow[nt * 16 + ml];         // W[n][k..k+8]
        acc[nt] = __builtin_amdgcn_mfma_f32_16x16x32_bf16(af, bfr, acc[nt], 0, 0, 0);
      }
    }
  }

  // Epilogue: C/D layout col = lane&15, row = quad*4 + reg.
#pragma unroll
  for (int nt = 0; nt < 8; ++nt) {
    int col = nt * 16 + ml;
    float bv = bias[col];
#pragma unroll
    for (int r = 0; r < 4; ++r) {
      int node = node0 + quad * 4 + r;
      if (node >= N_NODES) continue;
      float v = acc[nt][r] + bv;
      if (relu_bf16) {
        v = v > 0.f ? v : 0.f;
        out_bf16[(size_t)node * D + col] = f2b(v);
      } else {
        out_f32[(size_t)node * D + col] = v;
      }
    }
  }
}

extern "C" void kernel_launch(void* const* d_in, const int* in_sizes, int n_in,
                              void* d_out, int out_size, void* d_ws, size_t ws_size,
                              hipStream_t stream) {
  const float* x   = (const float*)d_in[0];
  const int*   ei  = (const int*)d_in[1];   // [2][E] int32
  const float* Wl0 = (const float*)d_in[2];
  const float* bl0 = (const float*)d_in[3];
  const float* Wr0 = (const float*)d_in[4];
  const float* Wl1 = (const float*)d_in[5];
  const float* bl1 = (const float*)d_in[6];
  const float* Wr1 = (const float*)d_in[7];
  float* out = (float*)d_out;

  char* ws = (char*)d_ws;
  size_t o = 0;
  auto carve = [&](size_t bytes) {
    char* p = ws + o;
    o += bytes;
    o = (o + 255) & ~(size_t)255;
    return p;
  };
  int* offs       = (int*)carve((size_t)(N_NODES + 1) * 4);
  int* csr        = (int*)carve((size_t)N_EDGES * 4);
  int* counts     = (int*)carve((size_t)NBIN * NBUCK * 4);
  unsigned* staging = (unsigned*)carve((size_t)NBIN * NBUCK * SCAP * 4);
  unsigned short* Bf   = (unsigned short*)carve((size_t)2 * 32 * 128 * 8 * 2);
  unsigned short* xb   = (unsigned short*)carve((size_t)N_NODES * D * 2);
  unsigned short* aggb = (unsigned short*)carve((size_t)N_NODES * D * 2);
  unsigned short* hb   = (unsigned short*)carve((size_t)N_NODES * D * 2);

  const int* srcp = ei;
  const int* dstp = ei + N_EDGES;

  setup_kernel<<<NBIN + NCONV + NPREP, 256, 0, stream>>>(
      x, xb, Wl0, Wr0, Wl1, Wr1, Bf, srcp, dstp, counts, staging);
  fill2_kernel<<<NBUCK, 1024, 0, stream>>>(staging, counts, offs, csr);

  const int GEMM_BLOCKS = (N_NODES + 63) / 64;
  // Layer 0: agg(x) ; h = relu([agg|x] @ [Wl0|Wr0]^T + b0) -> bf16
  agg_kernel<<<(N_NODES + 3) / 4, 256, 0, stream>>>(xb, csr, offs, aggb);
  gemm_kernel<<<GEMM_BLOCKS, 256, 0, stream>>>(aggb, xb, Bf, bl0, nullptr, hb, 1);
  // Layer 1: agg(h) ; out = [agg|h] @ [Wl1|Wr1]^T + b1 -> fp32
  agg_kernel<<<(N_NODES + 3) / 4, 256, 0, stream>>>(hb, csr, offs, aggb);
  gemm_kernel<<<GEMM_BLOCKS, 256, 0, stream>>>(aggb, hb, Bf + 32 * 128 * 8, bl1,
                                               out, nullptr, 0);
}

// Round 9
// 205.703 us; speedup vs baseline: 1.0720x; 1.0720x over previous
//
#include <hip/hip_runtime.h>

// SAGE 2-layer GraphSAGE (mean aggr) on MI355X.
// Pipeline: memset -> setup(bin+convert+prep) -> fill2 -> [agg -> gemm] x2.
//           (7 dispatches)  == R15 structure (measured best 206.4us) ==
// R1: hierarchical scan (single-block scan was 108us on 1 CU).
// R2: bucket-local CSR build (random scatter had 16x write amplification).
// R3: LDS-free GEMM w/ pre-formatted bf16 B-frags (bank conflicts + 2 blk/CU).
// R4-R6: fused setup (bin blocks FIRST in grid), fill2 block=1024.
// R7: REGRESSION: agg fused into gemm block cut agg waves 50000->3128 (79us).
//     agg must keep 1 wave/node.
// R8: best=228.0us.
// R9: REGRESSION (245us): NBIN 1568 fragmented staging; NBIN=784 optimum.
// R10: REGRESSION (288us): slice-phased agg. Bottleneck is NOT cache tier.
// R11: 215.7us. agg: coalesced csr + readlane broadcast + 8-deep gathers.
// R12: REGRESSION (228.7us): persistent agg. Wave retirement IS the pipeline.
// R13: NEUTRAL (218.6us): depth 8->16 alone. Load depth saturated.
// R14: 209.9us. Scalar-pipe diet: s_load indices, saddr gathers, v_pk_add_f32.
// R15: 206.4us (best). Single-wait 32-slot batch for deg<=31. agg within ~15%
//      of its request-path floor (~3.2M compulsory 64B lines @ ~5-6 TB/s).
// R16/R17: REGRESSION (220.5us): per-(binblock,bucket) slice staging. fill2's
//      column-sum made every block read the whole 784x196 counts matrix
//      (~120MB redundant) + serialized slice walks. Dense staging was right.
// R18: R15 exactly + bin path caches (dst,src) in regs across both passes:
//      scatter pass issues ZERO loads (was re-reading dst+src, 6.4MB).

typedef __attribute__((ext_vector_type(8))) short short8;
typedef __attribute__((ext_vector_type(4))) float f32x4;
typedef __attribute__((ext_vector_type(2))) float f32x2;

#define DEV __device__ __forceinline__

DEV unsigned short f2b(float f) {
  unsigned u = __builtin_bit_cast(unsigned, f);
  u += 0x7fffu + ((u >> 16) & 1u);   // round-to-nearest-even
  return (unsigned short)(u >> 16);
}
DEV float b2f(unsigned short h) {
  unsigned u = ((unsigned)h) << 16;
  return __builtin_bit_cast(float, u);
}
DEV float bitf(unsigned u) { return __builtin_bit_cast(float, u); }

constexpr int N_NODES = 50000;
constexpr int N_EDGES = 800000;
constexpr int D = 128;
constexpr int NBUCK = (N_NODES + 255) / 256;          // 196 buckets of 256 nodes
constexpr int BCAP = 5120;                            // mean 4096, +16 sigma
constexpr int NBIN = 784;                             // bin blocks (3/CU) - measured optimum
constexpr int EPB = (N_EDGES + NBIN - 1) / NBIN;      // 1021 edges per bin block
constexpr int KITER = (EPB + 255) / 256;              // 4 reg-cached iters/thread
constexpr int NCONV = (N_NODES * D / 4) / 256;        // 6250 convert blocks
constexpr int NPREP = (2 * 32 * 128) / 256;           // 32 prep blocks

// ---------------- fused setup: bin | convert | prep_weights ----------------
// bin blocks FIRST: latency-bound long pole; convert streams around them.
// R18: (dst,src) cached in registers across count+scatter passes.
__global__ __launch_bounds__(256) void setup_kernel(
    const float* __restrict__ x, unsigned short* __restrict__ xb,
    const float* __restrict__ Wl0, const float* __restrict__ Wr0,
    const float* __restrict__ Wl1, const float* __restrict__ Wr1,
    unsigned short* __restrict__ Bf,
    const int* __restrict__ src, const int* __restrict__ dst,
    int* __restrict__ g_bcnt, unsigned* __restrict__ staging) {
  __shared__ int cnt[NBUCK];
  __shared__ int cur[NBUCK];
  int bid = blockIdx.x;
  int t = threadIdx.x;

  if (bid < NBIN) {
    // bin: bucket edges, packed (dloc<<16)|src (src < 2^16)
    for (int i = t; i < NBUCK; i += 256) cnt[i] = 0;
    __syncthreads();
    int beg = bid * EPB;
    int end = min(beg + EPB, N_EDGES);
    int dv[KITER], sv[KITER];
#pragma unroll
    for (int k = 0; k < KITER; ++k) {
      int e = beg + t + k * 256;
      if (e < end) {
        dv[k] = dst[e];
        sv[k] = src[e];
        atomicAdd(&cnt[dv[k] >> 8], 1);
      }
    }
    __syncthreads();
    for (int i = t; i < NBUCK; i += 256) {
      cur[i] = atomicAdd(&g_bcnt[i], cnt[i]);   // contiguous chunk base
    }
    __syncthreads();
#pragma unroll
    for (int k = 0; k < KITER; ++k) {
      int e = beg + t + k * 256;
      if (e < end) {
        int d = dv[k];
        int b = d >> 8;
        int p = atomicAdd(&cur[b], 1);
        if (p >= BCAP) p = BCAP - 1;  // paranoia; statistically unreachable
        staging[b * BCAP + p] = ((unsigned)(d & 255) << 16) | (unsigned)sv[k];
      }
    }
    return;
  }
  if (bid < NBIN + NCONV) {
    // fp32 -> bf16 feature convert
    int i = (bid - NBIN) * 256 + t;
    f32x4 v = ((const f32x4*)x)[i];
    uint2 o;
    o.x = (unsigned)f2b(v.x) | ((unsigned)f2b(v.y) << 16);
    o.y = (unsigned)f2b(v.z) | ((unsigned)f2b(v.w) << 16);
    ((uint2*)xb)[i] = o;
    return;
  }
  // weights fp32 [out][in] -> bf16 B-fragment order (frag = kchunk*128+n)
  int f = (bid - NBIN - NCONV) * 256 + t;
  int layer = f >> 12;
  int kchunk = (f >> 7) & 31;
  int n = f & 127;
  const float* W;
  if (layer == 0) W = (kchunk < 16) ? Wl0 : Wr0;
  else            W = (kchunk < 16) ? Wl1 : Wr1;
  int k = (kchunk & 15) * 8;
  const f32x4* row = (const f32x4*)(W + n * D + k);
  f32x4 a = row[0], b = row[1];
  uint4 pk;
  pk.x = (unsigned)f2b(a.x) | ((unsigned)f2b(a.y) << 16);
  pk.y = (unsigned)f2b(a.z) | ((unsigned)f2b(a.w) << 16);
  pk.z = (unsigned)f2b(b.x) | ((unsigned)f2b(b.y) << 16);
  pk.w = (unsigned)f2b(b.z) | ((unsigned)f2b(b.w) << 16);
  *(uint4*)(Bf + (size_t)f * 8) = pk;
}

// ---------------- fill2: inline bucket scan + per-bucket CSR fill ----------
__global__ __launch_bounds__(1024) void fill2_kernel(const unsigned* __restrict__ staging,
                                                     const int* __restrict__ g_bcnt,
                                                     int* __restrict__ offs,
                                                     int* __restrict__ csr) {
  __shared__ int cnts[256];
  __shared__ int tmp[256];
  __shared__ int hist[256];
  __shared__ int cur[256];
  __shared__ int sh_n, sh_bb;
  int b = blockIdx.x;
  int t = threadIdx.x;
  if (t < 256) {
    int c = (t < NBUCK) ? g_bcnt[t] : 0;
    cnts[t] = c;
    tmp[t] = c;
    hist[t] = 0;
  }
  __syncthreads();
  if (t < 256) {
    for (int off = 1; off < 256; off <<= 1) {
      int u = (t >= off) ? tmp[t - off] : 0;
      __syncthreads();
      tmp[t] += u;
      __syncthreads();
    }
  } else {
    for (int off = 1; off < 256; off <<= 1) { __syncthreads(); __syncthreads(); }
  }
  if (t == 0) {
    sh_n = cnts[b];
    sh_bb = tmp[b] - cnts[b];   // exclusive prefix for this bucket
  }
  __syncthreads();
  int n = sh_n;
  int bb = sh_bb;
  if (b == 0 && t == 0) offs[N_NODES] = N_EDGES;

  const unsigned* st = staging + b * BCAP;
  for (int e = t; e < n; e += 1024) atomicAdd(&hist[st[e] >> 16], 1);
  __syncthreads();
  if (t < 256) {
    int v = hist[t];
    tmp[t] = v;
    __syncthreads();
    for (int off = 1; off < 256; off <<= 1) {
      int u = (t >= off) ? tmp[t - off] : 0;
      __syncthreads();
      tmp[t] += u;
      __syncthreads();
    }
    int excl = tmp[t] - v;
    int node = b * 256 + t;
    if (node < N_NODES) offs[node] = bb + excl;
    cur[t] = bb + excl;
  } else {
    __syncthreads();
    for (int off = 1; off < 256; off <<= 1) { __syncthreads(); __syncthreads(); }
  }
  __syncthreads();
  for (int e = t; e < n; e += 1024) {
    unsigned pk = st[e];
    int p = atomicAdd(&cur[pk >> 16], 1);
    csr[p] = (int)(pk & 0xffffu);
  }
}

// ---------------- mean aggregation: one wave per node ----------------
// 50000 waves; each lane owns one dword (2 cols); fp32 accumulate.
// R14: uniform wave id -> offs/csr via scalar loads, saddr gathers,
//      f32x2 accumulator (v_pk_add_f32). ~3 VALU/edge.
// R15: deg<=31 (99.6% of nodes): ONE 32-slot gather batch -> one wait.
__global__ __launch_bounds__(256) void agg_kernel(
    const unsigned short* __restrict__ feat,
    const int* __restrict__ csr_src,
    const int* __restrict__ offs,
    unsigned short* __restrict__ out) {
  int wv = __builtin_amdgcn_readfirstlane((int)(threadIdx.x >> 6));
  int w = (int)blockIdx.x * 4 + wv;
  int lane = threadIdx.x & 63;
  if (w >= N_NODES) return;
  int s = __builtin_amdgcn_readfirstlane(offs[w]);
  int e = __builtin_amdgcn_readfirstlane(offs[w + 1]);
  int deg = e - s;
  const unsigned* f = (const unsigned*)feat;  // 64 dwords per row
  const int* p = csr_src + s;                 // uniform base -> s_load
  f32x2 acc = {0.f, 0.f};

  if (deg <= 31) {
    // single gather round: issue everything, then one wait at first use.
    unsigned u[32];
#pragma unroll
    for (int jb = 0; jb < 32; jb += 4) {
      if (jb < deg) {
#pragma unroll
        for (int j2 = 0; j2 < 4; ++j2) {
          unsigned sj = (unsigned)p[jb + j2] & 0xFFFFu;  // clamped over-read
          u[jb + j2] = f[(sj << 6) + lane];
        }
      }
    }
#pragma unroll
    for (int j = 0; j < 32; ++j) {
      if (j < deg) {
        f32x2 v = {bitf(u[j] << 16), bitf(u[j] & 0xffff0000u)};
        acc += v;                                // v_pk_add_f32
      }
    }
  } else {
    // rare (P ~ 0.4%): R14 batched loop
    int c = 0;
    for (; c + 16 <= deg; c += 16) {
      unsigned u[16];
#pragma unroll
      for (int j = 0; j < 16; ++j) {
        int sj = p[c + j];
        u[j] = f[((unsigned)sj << 6) + lane];
      }
#pragma unroll
      for (int j = 0; j < 16; ++j) {
        f32x2 v = {bitf(u[j] << 16), bitf(u[j] & 0xffff0000u)};
        acc += v;
      }
    }
    int nb = deg - c;
    unsigned u[16];
#pragma unroll
    for (int j = 0; j < 16; ++j) {
      if (j < nb) {
        int sj = p[c + j];
        u[j] = f[((unsigned)sj << 6) + lane];
      }
    }
#pragma unroll
    for (int j = 0; j < 16; ++j) {
      if (j < nb) {
        f32x2 v = {bitf(u[j] << 16), bitf(u[j] & 0xffff0000u)};
        acc += v;
      }
    }
  }

  float inv = 1.0f / (float)max(deg, 1);
  unsigned o = (unsigned)f2b(acc.x * inv) | ((unsigned)f2b(acc.y * inv) << 16);
  ((unsigned*)out)[(size_t)w * 64 + lane] = o;
}

// ---------------- LDS-free fused SAGE GEMM, 16 nodes/wave ----------------
// out[i,:] = Aagg[i,:] @ Wl^T + Afeat[i,:] @ Wr^T + bias  (+optional ReLU)
// 782 blocks x 4 waves = 3128 waves (measured optimum vs 1564 / 6252).
__global__ __launch_bounds__(256) void gemm_kernel(
    const unsigned short* __restrict__ Aagg,   // [N][128] bf16
    const unsigned short* __restrict__ Afeat,  // [N][128] bf16
    const unsigned short* __restrict__ Bf,     // frag-ordered weights, this layer
    const float* __restrict__ bias,            // [128]
    float* __restrict__ out_f32,               // used if relu_bf16 == 0
    unsigned short* __restrict__ out_bf16,     // used if relu_bf16 == 1
    int relu_bf16) {
  int wave = threadIdx.x >> 6;
  int lane = threadIdx.x & 63;
  int ml = lane & 15;     // A: m / B: n / C: col
  int quad = lane >> 4;   // A,B: k-sub / C: row group
  int node0 = blockIdx.x * 64 + wave * 16;

  int arow = node0 + ml;
  if (arow >= N_NODES) arow = N_NODES - 1;  // clamp; stores guarded below

  f32x4 acc[8];
#pragma unroll
  for (int t = 0; t < 8; ++t) acc[t] = (f32x4){0.f, 0.f, 0.f, 0.f};

  const short8* bf8 = (const short8*)Bf;  // frag idx = kchunk*128 + n
#pragma unroll
  for (int mat = 0; mat < 2; ++mat) {
    const unsigned short* A = mat ? Afeat : Aagg;
    const short8* arow8 = (const short8*)(A + (size_t)arow * D);  // 16 frags/row
    int kbase = mat * 16;
#pragma unroll
    for (int kc = 0; kc < 4; ++kc) {
      short8 af = arow8[kc * 4 + quad];          // A[m][kc*32 + quad*8 ..+8]
      int kchunk = kbase + kc * 4 + quad;
      const short8* brow = bf8 + kchunk * 128;
#pragma unroll
      for (int nt = 0; nt < 8; ++nt) {
        short8 bfr = brow[nt * 16 + ml];         // W[n][k..k+8]
        acc[nt] = __builtin_amdgcn_mfma_f32_16x16x32_bf16(af, bfr, acc[nt], 0, 0, 0);
      }
    }
  }

  // Epilogue: C/D layout col = lane&15, row = quad*4 + reg.
#pragma unroll
  for (int nt = 0; nt < 8; ++nt) {
    int col = nt * 16 + ml;
    float bv = bias[col];
#pragma unroll
    for (int r = 0; r < 4; ++r) {
      int node = node0 + quad * 4 + r;
      if (node >= N_NODES) continue;
      float v = acc[nt][r] + bv;
      if (relu_bf16) {
        v = v > 0.f ? v : 0.f;
        out_bf16[(size_t)node * D + col] = f2b(v);
      } else {
        out_f32[(size_t)node * D + col] = v;
      }
    }
  }
}

extern "C" void kernel_launch(void* const* d_in, const int* in_sizes, int n_in,
                              void* d_out, int out_size, void* d_ws, size_t ws_size,
                              hipStream_t stream) {
  const float* x   = (const float*)d_in[0];
  const int*   ei  = (const int*)d_in[1];   // [2][E] int32
  const float* Wl0 = (const float*)d_in[2];
  const float* bl0 = (const float*)d_in[3];
  const float* Wr0 = (const float*)d_in[4];
  const float* Wl1 = (const float*)d_in[5];
  const float* bl1 = (const float*)d_in[6];
  const float* Wr1 = (const float*)d_in[7];
  float* out = (float*)d_out;

  char* ws = (char*)d_ws;
  size_t o = 0;
  auto carve = [&](size_t bytes) {
    char* p = ws + o;
    o += bytes;
    o = (o + 255) & ~(size_t)255;
    return p;
  };
  int* offs       = (int*)carve((size_t)(N_NODES + 1) * 4);
  int* csr        = (int*)carve((size_t)N_EDGES * 4);
  int* g_bcnt     = (int*)carve((size_t)NBUCK * 4);
  unsigned* staging = (unsigned*)carve((size_t)NBUCK * BCAP * 4);
  unsigned short* Bf   = (unsigned short*)carve((size_t)2 * 32 * 128 * 8 * 2);
  unsigned short* xb   = (unsigned short*)carve((size_t)N_NODES * D * 2);
  unsigned short* aggb = (unsigned short*)carve((size_t)N_NODES * D * 2);
  unsigned short* hb   = (unsigned short*)carve((size_t)N_NODES * D * 2);

  const int* srcp = ei;
  const int* dstp = ei + N_EDGES;

  hipMemsetAsync(g_bcnt, 0, (size_t)NBUCK * 4, stream);
  setup_kernel<<<NBIN + NCONV + NPREP, 256, 0, stream>>>(
      x, xb, Wl0, Wr0, Wl1, Wr1, Bf, srcp, dstp, g_bcnt, staging);
  fill2_kernel<<<NBUCK, 1024, 0, stream>>>(staging, g_bcnt, offs, csr);

  const int GEMM_BLOCKS = (N_NODES + 63) / 64;
  // Layer 0: agg(x) ; h = relu([agg|x] @ [Wl0|Wr0]^T + b0) -> bf16
  agg_kernel<<<(N_NODES + 3) / 4, 256, 0, stream>>>(xb, csr, offs, aggb);
  gemm_kernel<<<GEMM_BLOCKS, 256, 0, stream>>>(aggb, xb, Bf, bl0, nullptr, hb, 1);
  // Layer 1: agg(h) ; out = [agg|h] @ [Wl1|Wr1]^T + b1 -> fp32
  agg_kernel<<<(N_NODES + 3) / 4, 256, 0, stream>>>(hb, csr, offs, aggb);
  gemm_kernel<<<GEMM_BLOCKS, 256, 0, stream>>>(aggb, hb, Bf + 32 * 128 * 8, bl1,
                                               out, nullptr, 0);
}